// Round 9
// baseline (400.110 us; speedup 1.0000x reference)
//
#include <hip/hip_runtime.h>
#include <hip/hip_bf16.h>
#include <math.h>

#define D 256

typedef short s16x8 __attribute__((ext_vector_type(8)));
typedef float f32x4 __attribute__((ext_vector_type(4)));

__device__ __forceinline__ unsigned short f2bf(float f) {
    unsigned int u = __builtin_bit_cast(unsigned int, f);
    unsigned int r = (u + 0x7fffu + ((u >> 16) & 1u)) >> 16;  // RNE
    return (unsigned short)r;
}
__device__ __forceinline__ float bf2f(unsigned short s) {
    unsigned int u = ((unsigned int)s) << 16;
    return __builtin_bit_cast(float, u);
}

// ---- pre: W-swizzle + row_ptr build + X -> bf16 convert, one kernel (frozen, round 8) ----
__global__ void pre_all(const float* __restrict__ X,
                        const float* __restrict__ W1, const float* __restrict__ Wr,
                        unsigned short* __restrict__ Xbf,
                        unsigned short* __restrict__ W1sw, unsigned short* __restrict__ Wrsw,
                        const int* __restrict__ rows, int* __restrict__ rp,
                        int N, int E, int rpBlocks) {
    int bid = blockIdx.x;
    if (bid < 512) {
        int idx = bid * 256 + threadIdx.x;  // 0 .. 131071
        int m = idx >> 16;
        int t = idx & 65535;
        const float* src = m ? Wr : W1;
        unsigned short* dst = m ? Wrsw : W1sw;
        int j = t & 7, lane = (t >> 3) & 63, nt = (t >> 9) & 15, kt = t >> 13;
        int k = kt * 32 + (lane >> 4) * 8 + j;
        int n = nt * 16 + (lane & 15);
        dst[t] = f2bf(src[k * D + n]);
    } else if (bid < 512 + rpBlocks) {
        int r = (bid - 512) * 256 + threadIdx.x;
        if (r > N) return;
        int lo = 0, hi = E;
        while (lo < hi) {
            int mid = (lo + hi) >> 1;
            if (rows[mid] < r) lo = mid + 1; else hi = mid;
        }
        rp[r] = lo;
    } else {
        long long c = (long long)(bid - 512 - rpBlocks) * 256 + threadIdx.x;
        long long i8 = c * 8;
        if (i8 >= (long long)N * D) return;
        float4 f0 = *(const float4*)(X + i8);
        float4 f1 = *(const float4*)(X + i8 + 4);
        s16x8 sf;
        sf[0] = (short)f2bf(f0.x); sf[1] = (short)f2bf(f0.y);
        sf[2] = (short)f2bf(f0.z); sf[3] = (short)f2bf(f0.w);
        sf[4] = (short)f2bf(f1.x); sf[5] = (short)f2bf(f1.y);
        sf[6] = (short)f2bf(f1.z); sf[7] = (short)f2bf(f1.w);
        *(s16x8*)(Xbf + i8) = sf;
    }
}

// ---------------- Scatter on Xbf: aggX = A * Xbf (no relu) — frozen, round 8 ----------
__device__ __forceinline__ void acc4(float4& a, uint2 u, float v) {
    float x0 = __builtin_bit_cast(float, u.x << 16);
    float x1 = __builtin_bit_cast(float, u.x & 0xffff0000u);
    float x2 = __builtin_bit_cast(float, u.y << 16);
    float x3 = __builtin_bit_cast(float, u.y & 0xffff0000u);
    a.x += v * x0; a.y += v * x1; a.z += v * x2; a.w += v * x3;
}

__global__ __launch_bounds__(256) void scatter_x(const uint2* __restrict__ xp,
                                                 const int* __restrict__ rp,
                                                 const int* __restrict__ cols,
                                                 const float* __restrict__ vals,
                                                 uint2* __restrict__ aggp,
                                                 int N, int E) {
    int lane = threadIdx.x & 63;
    int wave = threadIdx.x >> 6;
    int row = blockIdx.x * 4 + wave;
    if (row >= N) return;
    int start = rp[row], end = rp[row + 1];

    float4 a = {0.f, 0.f, 0.f, 0.f};
    for (int base = start; base < end; base += 64) {
        int ii = base + lane;
        int iic = ii < E ? ii : E - 1;
        int cl = cols[iic];
        int vbits = __builtin_bit_cast(int, vals[iic]);
        int n = end - base; if (n > 64) n = 64;
        int i = 0;
        for (; i + 8 <= n; i += 8) {
            uint2 u[8]; float vv[8];
#pragma unroll
            for (int k = 0; k < 8; k++) {
                int c = __builtin_amdgcn_readlane(cl, i + k);
                vv[k] = __builtin_bit_cast(float, __builtin_amdgcn_readlane(vbits, i + k));
                u[k] = xp[(size_t)c * 64 + lane];
            }
#pragma unroll
            for (int k = 0; k < 8; k++) acc4(a, u[k], vv[k]);
        }
        for (; i < n; i++) {
            int c = __builtin_amdgcn_readlane(cl, i);
            float v = __builtin_bit_cast(float, __builtin_amdgcn_readlane(vbits, i));
            uint2 u = xp[(size_t)c * 64 + lane];
            acc4(a, u, v);
        }
    }
    uint2 o;
    o.x = (unsigned int)f2bf(a.x) | ((unsigned int)f2bf(a.y) << 16);
    o.y = (unsigned int)f2bf(a.z) | ((unsigned int)f2bf(a.w) << 16);
    aggp[(size_t)row * 64 + lane] = o;
}

// ---------------- gemm_ff2: 2 tiles/block, W loaded once per block -------------------
// Phase1 (W1 in bfr): acc1 = aggX @ W1 for tiles t0,t1; relu + pack gcn to bf16 in regs.
// Swap bfr -> Wr. Phase2: acc2 = Xbf[perm] @ Wr (A via LDS); epilogue blends.
__global__ __launch_bounds__(512) void gemm_ff2(const unsigned short* __restrict__ aggX,
                                                const unsigned short* __restrict__ Xbf,
                                                const int* __restrict__ perm,
                                                const unsigned short* __restrict__ W1sw,
                                                const unsigned short* __restrict__ Wrsw,
                                                const float* __restrict__ br,
                                                float* __restrict__ out,
                                                int N, int numTiles) {
    __shared__ unsigned short lA[2][8192];  // 2 x 16 KB: left frags per tile
    int t = threadIdx.x;
    int lane = t & 63;
    int wave = t >> 6;
    int quad = lane >> 4;
    int t0 = blockIdx.x * 2;
    int nT = (t0 + 1 < numTiles) ? 2 : 1;

    // ---- stage left = Xbf[perm[rows]] for both tiles ----
    for (int tt = 0; tt < nT; tt++) {
        int tile = t0 + tt;
#pragma unroll
        for (int q = 0; q < 2; q++) {
            int fgi = q * 512 + t;
            int mt = fgi >> 9, kt = (fgi >> 6) & 7, ll = fgi & 63;
            int rl = ll & 15, qd = ll >> 4;
            int grow = tile * 32 + mt * 16 + rl;
            if (grow >= N) grow = N - 1;
            int pr = perm[grow];
            *(s16x8*)(&lA[tt][(size_t)fgi * 8]) =
                *(const s16x8*)(Xbf + (size_t)pr * D + kt * 32 + qd * 8);
        }
    }

    // ---- W1 fragments ----
    s16x8 bfr[2][8];
#pragma unroll
    for (int ntl = 0; ntl < 2; ntl++) {
        int nt = wave * 2 + ntl;
#pragma unroll
        for (int kt = 0; kt < 8; kt++)
            bfr[ntl][kt] = *(const s16x8*)(W1sw + ((size_t)((kt * 16 + nt) * 64 + lane)) * 8);
    }

    // ---- phase 1 for both tiles: gcn packed bf16 in registers ----
    unsigned int g1[2][8];
    for (int tt = 0; tt < nT; tt++) {
        int tile = t0 + tt;
        f32x4 acc[2][2];
#pragma unroll
        for (int mt = 0; mt < 2; mt++)
#pragma unroll
            for (int ntl = 0; ntl < 2; ntl++) acc[mt][ntl] = (f32x4){0.f, 0.f, 0.f, 0.f};
#pragma unroll
        for (int mt = 0; mt < 2; mt++) {
            int grow = tile * 32 + mt * 16 + (lane & 15);
            if (grow >= N) grow = N - 1;
            const unsigned short* ap = aggX + (size_t)grow * D + (lane >> 4) * 8;
#pragma unroll
            for (int kt = 0; kt < 8; kt++) {
                s16x8 a = *(const s16x8*)(ap + kt * 32);
                acc[mt][0] = __builtin_amdgcn_mfma_f32_16x16x32_bf16(a, bfr[0][kt], acc[mt][0], 0, 0, 0);
                acc[mt][1] = __builtin_amdgcn_mfma_f32_16x16x32_bf16(a, bfr[1][kt], acc[mt][1], 0, 0, 0);
            }
        }
        // relu + pack to bf16 pairs: g1[tt][(mt*2+ntl)*2 + r/2]
#pragma unroll
        for (int mt = 0; mt < 2; mt++)
#pragma unroll
            for (int ntl = 0; ntl < 2; ntl++)
#pragma unroll
                for (int rp2 = 0; rp2 < 2; rp2++) {
                    float e0 = fmaxf(acc[mt][ntl][2 * rp2], 0.f);
                    float e1 = fmaxf(acc[mt][ntl][2 * rp2 + 1], 0.f);
                    g1[tt][(mt * 2 + ntl) * 2 + rp2] =
                        (unsigned int)f2bf(e0) | ((unsigned int)f2bf(e1) << 16);
                }
    }

    // ---- swap to Wr fragments (register reuse) ----
#pragma unroll
    for (int ntl = 0; ntl < 2; ntl++) {
        int nt = wave * 2 + ntl;
#pragma unroll
        for (int kt = 0; kt < 8; kt++)
            bfr[ntl][kt] = *(const s16x8*)(Wrsw + ((size_t)((kt * 16 + nt) * 64 + lane)) * 8);
    }
    __syncthreads();  // lA staging visible

    // ---- phase 2 + epilogue per tile ----
    for (int tt = 0; tt < nT; tt++) {
        int tile = t0 + tt;
        f32x4 acc[2][2];
#pragma unroll
        for (int mt = 0; mt < 2; mt++)
#pragma unroll
            for (int ntl = 0; ntl < 2; ntl++) acc[mt][ntl] = (f32x4){0.f, 0.f, 0.f, 0.f};
#pragma unroll
        for (int mt = 0; mt < 2; mt++)
#pragma unroll
            for (int kt = 0; kt < 8; kt++) {
                s16x8 a = *(const s16x8*)(&lA[tt][(size_t)(((mt * 8 + kt) * 64 + lane)) * 8]);
                acc[mt][0] = __builtin_amdgcn_mfma_f32_16x16x32_bf16(a, bfr[0][kt], acc[mt][0], 0, 0, 0);
                acc[mt][1] = __builtin_amdgcn_mfma_f32_16x16x32_bf16(a, bfr[1][kt], acc[mt][1], 0, 0, 0);
            }
#pragma unroll
        for (int mt = 0; mt < 2; mt++) {
#pragma unroll
            for (int ntl = 0; ntl < 2; ntl++) {
                int col = (wave * 2 + ntl) * 16 + (lane & 15);
                float b = br[col];
                int kt2 = col >> 5, qd2 = (col >> 3) & 3, j2 = col & 7;
#pragma unroll
                for (int r = 0; r < 4; r++) {
                    int rt = mt * 16 + quad * 4 + r;
                    int grow = tile * 32 + rt;
                    if (grow < N) {
                        float pre = acc[mt][ntl][r] + b;
                        float gate = 1.f / (1.f + __expf(-pre));
                        unsigned int gp = g1[tt][(mt * 2 + ntl) * 2 + (r >> 1)];
                        float gcn = bf2f((unsigned short)((r & 1) ? (gp >> 16) : (gp & 0xffffu)));
                        float left = bf2f(lA[tt][(size_t)(((mt * 8 + kt2) * 64 + qd2 * 16 + (rt & 15))) * 8 + j2]);
                        out[(size_t)grow * D + col] = gate * gcn + (1.f - gate) * left;
                    }
                }
            }
        }
    }
}

extern "C" void kernel_launch(void* const* d_in, const int* in_sizes, int n_in,
                              void* d_out, int out_size, void* d_ws, size_t ws_size,
                              hipStream_t stream) {
    const float* right = (const float*)d_in[0];
    const float* W1    = (const float*)d_in[1];
    const float* Wr    = (const float*)d_in[2];
    const float* br    = (const float*)d_in[3];
    const float* evals = (const float*)d_in[4];
    const int*   erows = (const int*)d_in[5];
    const int*   ecols = (const int*)d_in[6];
    const int*   perm  = (const int*)d_in[7];
    int N = in_sizes[7];
    int E = in_sizes[4];
    float* out = (float*)d_out;

    char* ws = (char*)d_ws;
    unsigned short* W1sw = (unsigned short*)ws;
    unsigned short* Wrsw = W1sw + D * D;
    int* rp = (int*)(ws + (size_t)2 * D * D * 2);
    size_t off = (size_t)2 * D * D * 2 + 4 * (size_t)(N + 1);
    off = (off + 255) & ~(size_t)255;
    unsigned short* Xbf = (unsigned short*)(ws + off);
    unsigned short* aggX = Xbf + (size_t)N * D;

    int numTiles = (N + 31) / 32;
    int rpBlocks = (N + 256) / 256;
    long long cvtElems = (long long)N * D / 8;
    int cvtBlocks = (int)((cvtElems + 255) / 256);
    int ffBlocks = (numTiles + 1) / 2;

    pre_all<<<512 + rpBlocks + cvtBlocks, 256, 0, stream>>>(right, W1, Wr, Xbf, W1sw, Wrsw,
                                                            erows, rp, N, E, rpBlocks);
    scatter_x<<<(N + 3) / 4, 256, 0, stream>>>((const uint2*)Xbf, rp, ecols, evals,
                                               (uint2*)aggX, N, E);
    gemm_ff2<<<ffBlocks, 512, 0, stream>>>(aggX, Xbf, perm, W1sw, Wrsw, br, out, N, numTiles);
}

// Round 10
// 393.489 us; speedup vs baseline: 1.0168x; 1.0168x over previous
//
#include <hip/hip_runtime.h>
#include <hip/hip_bf16.h>
#include <math.h>

#define D 256

typedef short s16x8 __attribute__((ext_vector_type(8)));
typedef float f32x4 __attribute__((ext_vector_type(4)));

__device__ __forceinline__ unsigned short f2bf(float f) {
    unsigned int u = __builtin_bit_cast(unsigned int, f);
    unsigned int r = (u + 0x7fffu + ((u >> 16) & 1u)) >> 16;  // RNE
    return (unsigned short)r;
}
__device__ __forceinline__ float bf2f(unsigned short s) {
    unsigned int u = ((unsigned int)s) << 16;
    return __builtin_bit_cast(float, u);
}

// ---- pre: W-swizzle + row_ptr build + X -> bf16 convert, one kernel (frozen, round 8) ----
__global__ void pre_all(const float* __restrict__ X,
                        const float* __restrict__ W1, const float* __restrict__ Wr,
                        unsigned short* __restrict__ Xbf,
                        unsigned short* __restrict__ W1sw, unsigned short* __restrict__ Wrsw,
                        const int* __restrict__ rows, int* __restrict__ rp,
                        int N, int E, int rpBlocks) {
    int bid = blockIdx.x;
    if (bid < 512) {
        int idx = bid * 256 + threadIdx.x;  // 0 .. 131071
        int m = idx >> 16;
        int t = idx & 65535;
        const float* src = m ? Wr : W1;
        unsigned short* dst = m ? Wrsw : W1sw;
        int j = t & 7, lane = (t >> 3) & 63, nt = (t >> 9) & 15, kt = t >> 13;
        int k = kt * 32 + (lane >> 4) * 8 + j;
        int n = nt * 16 + (lane & 15);
        dst[t] = f2bf(src[k * D + n]);
    } else if (bid < 512 + rpBlocks) {
        int r = (bid - 512) * 256 + threadIdx.x;
        if (r > N) return;
        int lo = 0, hi = E;
        while (lo < hi) {
            int mid = (lo + hi) >> 1;
            if (rows[mid] < r) lo = mid + 1; else hi = mid;
        }
        rp[r] = lo;
    } else {
        long long c = (long long)(bid - 512 - rpBlocks) * 256 + threadIdx.x;
        long long i8 = c * 8;
        if (i8 >= (long long)N * D) return;
        float4 f0 = *(const float4*)(X + i8);
        float4 f1 = *(const float4*)(X + i8 + 4);
        s16x8 sf;
        sf[0] = (short)f2bf(f0.x); sf[1] = (short)f2bf(f0.y);
        sf[2] = (short)f2bf(f0.z); sf[3] = (short)f2bf(f0.w);
        sf[4] = (short)f2bf(f1.x); sf[5] = (short)f2bf(f1.y);
        sf[6] = (short)f2bf(f1.z); sf[7] = (short)f2bf(f1.w);
        *(s16x8*)(Xbf + i8) = sf;
    }
}

// ---------------- scatter_x4: 2 edges per wave-instruction, uint4 (16B) gathers ---------
// Wave = 1 row. half = lane>>5 selects edge of the pair, ci = lane&31 selects the 16B
// chunk (8 cols) of the 512B row. 8 uint4 loads in flight (16 edges) per unroll group.
// Cross-half shfl_xor(32) reduction, half-wave uint4 store.
__global__ __launch_bounds__(256) void scatter_x4(const uint4* __restrict__ xp4,
                                                  const int* __restrict__ rp,
                                                  const int* __restrict__ cols,
                                                  const float* __restrict__ vals,
                                                  uint4* __restrict__ aggp4,
                                                  int N, int E) {
    int lane = threadIdx.x & 63;
    int wave = threadIdx.x >> 6;
    int row = blockIdx.x * 4 + wave;
    if (row >= N) return;
    int start = rp[row], end = rp[row + 1];
    int half = lane >> 5;
    int ci = lane & 31;

    float a[8];
#pragma unroll
    for (int j = 0; j < 8; j++) a[j] = 0.f;

    for (int base = start; base < end; base += 64) {
        int ii = base + lane;
        int iic = ii < E ? ii : E - 1;
        int cl = cols[iic];
        int vb = __builtin_bit_cast(int, vals[iic]);
        int n = end - base; if (n > 64) n = 64;
        for (int i = 0; i < n; i += 16) {
            uint4 u[8]; float vv[8];
#pragma unroll
            for (int s = 0; s < 8; s++) {
                int ei = i + 2 * s + half;
                int c  = __builtin_amdgcn_ds_bpermute(ei << 2, cl);
                int vx = __builtin_amdgcn_ds_bpermute(ei << 2, vb);
                bool ok = ei < n;
                vv[s] = ok ? __builtin_bit_cast(float, vx) : 0.f;
                int cc = ok ? c : 0;
                u[s] = xp4[(size_t)cc * 32 + ci];
            }
#pragma unroll
            for (int s = 0; s < 8; s++) {
                uint4 q = u[s]; float v = vv[s];
                a[0] += v * __builtin_bit_cast(float, q.x << 16);
                a[1] += v * __builtin_bit_cast(float, q.x & 0xffff0000u);
                a[2] += v * __builtin_bit_cast(float, q.y << 16);
                a[3] += v * __builtin_bit_cast(float, q.y & 0xffff0000u);
                a[4] += v * __builtin_bit_cast(float, q.z << 16);
                a[5] += v * __builtin_bit_cast(float, q.z & 0xffff0000u);
                a[6] += v * __builtin_bit_cast(float, q.w << 16);
                a[7] += v * __builtin_bit_cast(float, q.w & 0xffff0000u);
            }
        }
    }
#pragma unroll
    for (int j = 0; j < 8; j++) a[j] += __shfl_xor(a[j], 32, 64);
    if (half == 0) {
        uint4 o;
        o.x = (unsigned int)f2bf(a[0]) | ((unsigned int)f2bf(a[1]) << 16);
        o.y = (unsigned int)f2bf(a[2]) | ((unsigned int)f2bf(a[3]) << 16);
        o.z = (unsigned int)f2bf(a[4]) | ((unsigned int)f2bf(a[5]) << 16);
        o.w = (unsigned int)f2bf(a[6]) | ((unsigned int)f2bf(a[7]) << 16);
        aggp4[(size_t)row * 32 + ci] = o;
    }
}

// ---------------- gemm_ff: round-8 exact (best measured total) ----------------------
__global__ __launch_bounds__(512, 4) void gemm_ff(const unsigned short* __restrict__ aggX,
                                                  const unsigned short* __restrict__ Xbf,
                                                  const int* __restrict__ perm,
                                                  const unsigned short* __restrict__ W1sw,
                                                  const unsigned short* __restrict__ Wrsw,
                                                  const float* __restrict__ br,
                                                  float* __restrict__ out,
                                                  int N, int numTiles) {
    __shared__ unsigned short lA[8 * 64 * 16];  // 16 KB: left frags (bf16 Xbf[perm])
    int t = threadIdx.x;
    int lane = t & 63;
    int wave = t >> 6;
    int quad = lane >> 4;
    int tile = blockIdx.x;
    if (tile >= numTiles) return;

#pragma unroll
    for (int q = 0; q < 2; q++) {
        int fgi = q * 512 + t;
        int mt = fgi >> 9, kt = (fgi >> 6) & 7, ll = fgi & 63;
        int rl = ll & 15, qd = ll >> 4;
        int grow = tile * 32 + mt * 16 + rl;
        if (grow >= N) grow = N - 1;
        int pr = perm[grow];
        *(s16x8*)(lA + (size_t)fgi * 8) = *(const s16x8*)(Xbf + (size_t)pr * D + kt * 32 + qd * 8);
    }

    s16x8 bfr[2][8];
#pragma unroll
    for (int ntl = 0; ntl < 2; ntl++) {
        int nt = wave * 2 + ntl;
#pragma unroll
        for (int kt = 0; kt < 8; kt++)
            bfr[ntl][kt] = *(const s16x8*)(W1sw + ((size_t)((kt * 16 + nt) * 64 + lane)) * 8);
    }
    f32x4 acc1[2][2];
#pragma unroll
    for (int mt = 0; mt < 2; mt++)
#pragma unroll
        for (int ntl = 0; ntl < 2; ntl++) acc1[mt][ntl] = (f32x4){0.f, 0.f, 0.f, 0.f};

#pragma unroll
    for (int mt = 0; mt < 2; mt++) {
        int grow = tile * 32 + mt * 16 + (lane & 15);
        if (grow >= N) grow = N - 1;
        const unsigned short* ap = aggX + (size_t)grow * D + (lane >> 4) * 8;
#pragma unroll
        for (int kt = 0; kt < 8; kt++) {
            s16x8 a = *(const s16x8*)(ap + kt * 32);
            acc1[mt][0] = __builtin_amdgcn_mfma_f32_16x16x32_bf16(a, bfr[0][kt], acc1[mt][0], 0, 0, 0);
            acc1[mt][1] = __builtin_amdgcn_mfma_f32_16x16x32_bf16(a, bfr[1][kt], acc1[mt][1], 0, 0, 0);
        }
    }
    __syncthreads();

#pragma unroll
    for (int ntl = 0; ntl < 2; ntl++) {
        int nt = wave * 2 + ntl;
#pragma unroll
        for (int kt = 0; kt < 8; kt++)
            bfr[ntl][kt] = *(const s16x8*)(Wrsw + ((size_t)((kt * 16 + nt) * 64 + lane)) * 8);
    }
    f32x4 acc2[2][2];
#pragma unroll
    for (int mt = 0; mt < 2; mt++)
#pragma unroll
        for (int ntl = 0; ntl < 2; ntl++) acc2[mt][ntl] = (f32x4){0.f, 0.f, 0.f, 0.f};

#pragma unroll
    for (int mt = 0; mt < 2; mt++)
#pragma unroll
        for (int kt = 0; kt < 8; kt++) {
            s16x8 a = *(const s16x8*)(lA + (size_t)(((mt * 8 + kt) * 64 + lane)) * 8);
            acc2[mt][0] = __builtin_amdgcn_mfma_f32_16x16x32_bf16(a, bfr[0][kt], acc2[mt][0], 0, 0, 0);
            acc2[mt][1] = __builtin_amdgcn_mfma_f32_16x16x32_bf16(a, bfr[1][kt], acc2[mt][1], 0, 0, 0);
        }

#pragma unroll
    for (int mt = 0; mt < 2; mt++) {
#pragma unroll
        for (int ntl = 0; ntl < 2; ntl++) {
            int col = (wave * 2 + ntl) * 16 + (lane & 15);
            float b = br[col];
            int kt2 = col >> 5, qd2 = (col >> 3) & 3, j2 = col & 7;
#pragma unroll
            for (int r = 0; r < 4; r++) {
                int rt = mt * 16 + quad * 4 + r;
                int grow = tile * 32 + rt;
                if (grow < N) {
                    float pre = acc2[mt][ntl][r] + b;
                    float gate = 1.f / (1.f + __expf(-pre));
                    float gcn = fmaxf(acc1[mt][ntl][r], 0.f);
                    float left = bf2f(lA[(size_t)(((mt * 8 + kt2) * 64 + qd2 * 16 + (rt & 15))) * 8 + j2]);
                    out[(size_t)grow * D + col] = gate * gcn + (1.f - gate) * left;
                }
            }
        }
    }
}

extern "C" void kernel_launch(void* const* d_in, const int* in_sizes, int n_in,
                              void* d_out, int out_size, void* d_ws, size_t ws_size,
                              hipStream_t stream) {
    const float* right = (const float*)d_in[0];
    const float* W1    = (const float*)d_in[1];
    const float* Wr    = (const float*)d_in[2];
    const float* br    = (const float*)d_in[3];
    const float* evals = (const float*)d_in[4];
    const int*   erows = (const int*)d_in[5];
    const int*   ecols = (const int*)d_in[6];
    const int*   perm  = (const int*)d_in[7];
    int N = in_sizes[7];
    int E = in_sizes[4];
    float* out = (float*)d_out;

    char* ws = (char*)d_ws;
    unsigned short* W1sw = (unsigned short*)ws;
    unsigned short* Wrsw = W1sw + D * D;
    int* rp = (int*)(ws + (size_t)2 * D * D * 2);
    size_t off = (size_t)2 * D * D * 2 + 4 * (size_t)(N + 1);
    off = (off + 255) & ~(size_t)255;
    unsigned short* Xbf = (unsigned short*)(ws + off);
    unsigned short* aggX = Xbf + (size_t)N * D;

    int numTiles = (N + 31) / 32;
    int rpBlocks = (N + 256) / 256;
    long long cvtElems = (long long)N * D / 8;
    int cvtBlocks = (int)((cvtElems + 255) / 256);

    pre_all<<<512 + rpBlocks + cvtBlocks, 256, 0, stream>>>(right, W1, Wr, Xbf, W1sw, Wrsw,
                                                            erows, rp, N, E, rpBlocks);
    scatter_x4<<<(N + 3) / 4, 256, 0, stream>>>((const uint4*)Xbf, rp, ecols, evals,
                                                (uint4*)aggX, N, E);
    gemm_ff<<<numTiles, 512, 0, stream>>>(aggX, Xbf, perm, W1sw, Wrsw, br, out, N, numTiles);
}